// Round 13
// baseline (337.611 us; speedup 1.0000x reference)
//
#include <hip/hip_runtime.h>
#include <hip/hip_fp16.h>

#define N_NODES 50000
#define N_EDGES 600000
#define N_GRAPHS 64
#define N_LAYERS 4
#define D 128
#define BN_EPS 1e-5f

#define SCAN_NB 49   // ceil(50000/1024)
#define GB 782       // gemm grid (ceil(50000/64))
#define NBUCKET 32

// setup mega-kernel block ranges
#define EMB_NB 6250
#define ZERO_NB 14
#define RPK_NB 8

typedef __attribute__((ext_vector_type(8))) short short8;
typedef __attribute__((ext_vector_type(8))) _Float16 half8;
typedef __attribute__((ext_vector_type(4))) float f32x4;

#define WLO_SCALE 2048.0f
#define WLO_INV (1.0f / 2048.0f)

__device__ __forceinline__ float half_bits_to_f32(short b) {
  union { unsigned short u; __half h; } cv;
  cv.u = (unsigned short)b;
  return __half2float(cv.h);
}
__device__ __forceinline__ unsigned short f32_to_half_bits(float f) {
  union { __half h; unsigned short u; } cv;
  cv.h = __float2half(f);
  return cv.u;
}

// 64-lane exclusive prefix over the 49 scan partials; returns exclusive value in
// each lane (lane i holds prefix of partials[0..i)).
__device__ __forceinline__ int wave_partials_excl(const int* __restrict__ partials) {
  int lane = threadIdx.x & 63;
  int pv = (lane < SCAN_NB) ? partials[lane] : 0;
  int inc = pv;
#pragma unroll
  for (int o = 1; o < 64; o <<= 1) {
    int u = __shfl_up(inc, o, 64);
    if (lane >= o) inc += u;
  }
  return inc - pv;
}

// ---- setup mega-kernel: embed | zero(counts + stat buckets) | W repack ----
__global__ __launch_bounds__(256) void setup_kernel(const int* __restrict__ idx,
    const float* __restrict__ emb, __half* __restrict__ xh,
    int* __restrict__ counts, float* __restrict__ buckets,
    const float* __restrict__ cw1, const float* __restrict__ cw2,
    unsigned short* __restrict__ Wh, unsigned short* __restrict__ Wl) {
  int bb = blockIdx.x;
  int t = threadIdx.x;
  if (bb < EMB_NB) {
    int tid = bb * 256 + t;
    if (tid >= N_NODES * 32) return;
    int n = tid >> 5, c4 = tid & 31;
    int e = idx[n];
    float4 v = ((const float4*)emb)[(size_t)e * 32 + c4];
    __half2 a = __float22half2_rn(make_float2(v.x, v.y));
    __half2 b = __float22half2_rn(make_float2(v.z, v.w));
    ((__half2*)xh)[(size_t)tid * 2] = a;
    ((__half2*)xh)[(size_t)tid * 2 + 1] = b;
  } else if (bb < EMB_NB + ZERO_NB) {
    int tid = (bb - EMB_NB) * 256 + t;
    for (int i = tid; i < N_NODES; i += ZERO_NB * 256) counts[i] = 0;
    for (int i = tid; i < 16 * NBUCKET * 128; i += ZERO_NB * 256) buckets[i] = 0.f;
  } else {
    int b = bb - (EMB_NB + ZERO_NB);  // 0..7 = l*2 + which
    int l = b >> 1, which = b & 1;
    const float* Wm = (which ? cw2 : cw1) + (size_t)l * D * D;
    unsigned short* outh = Wh + (size_t)b * D * D;
    unsigned short* outl = Wl + (size_t)b * D * D;
    for (int T = t; T < 2048; T += 256) {
      int ks = T >> 9, ct = (T >> 6) & 7, lane = T & 63;
      int kbase = ks * 32 + ((lane >> 4) << 3);
      int c = ct * 16 + (lane & 15);
      unsigned short hs[8], ls[8];
#pragma unroll
      for (int e = 0; e < 8; ++e) {
        float v = Wm[(size_t)(kbase + e) * D + c];
        __half hh = __float2half_rn(v);
        float rem = v - __half2float(hh);
        __half hl = __float2half_rn(rem * WLO_SCALE);
        union { __half h; unsigned short u; } c1, c2;
        c1.h = hh; c2.h = hl;
        hs[e] = c1.u;
        ls[e] = c2.u;
      }
      *(ushort4*)(outh + (size_t)T * 8)     = *(ushort4*)&hs[0];
      *(ushort4*)(outh + (size_t)T * 8 + 4) = *(ushort4*)&hs[4];
      *(ushort4*)(outl + (size_t)T * 8)     = *(ushort4*)&ls[0];
      *(ushort4*)(outl + (size_t)T * 8 + 4) = *(ushort4*)&ls[4];
    }
  }
}

// ---------------- CSR build ----------------
__global__ __launch_bounds__(256) void count_kernel(const int* __restrict__ dst,
    int* __restrict__ counts) {
  int e = blockIdx.x * 256 + threadIdx.x;
  if (e < N_EDGES) atomicAdd(&counts[dst[e]], 1);
}

// scan within 1024-chunks; offsets/cursor hold CHUNK-LOCAL exclusive offsets.
// partials[b] = chunk b total. Last block also writes offsets[N_NODES] (local).
__global__ __launch_bounds__(256) void scan_block_kernel(const int* __restrict__ counts,
    int* __restrict__ offsets, int* __restrict__ cursor, int* __restrict__ partials) {
  __shared__ int s[256];
  int t = threadIdx.x;
  int base = blockIdx.x * 1024 + t * 4;
  int v[4];
#pragma unroll
  for (int i = 0; i < 4; ++i) v[i] = (base + i < N_NODES) ? counts[base + i] : 0;
  int tsum = v[0] + v[1] + v[2] + v[3];
  s[t] = tsum;
  __syncthreads();
  for (int off = 1; off < 256; off <<= 1) {
    int add = (t >= off) ? s[t - off] : 0;
    __syncthreads();
    s[t] += add;
    __syncthreads();
  }
  int run = s[t] - tsum;  // exclusive within block
#pragma unroll
  for (int i = 0; i < 4; ++i) {
    if (base + i < N_NODES) {
      offsets[base + i] = run;
      cursor[base + i] = run;
    }
    run += v[i];
  }
  if (t == 255) {
    partials[blockIdx.x] = s[255];
    if (blockIdx.x == SCAN_NB - 1) offsets[N_NODES] = s[255];
  }
}

// fill: local cursor + wave-scanned global prefix
__global__ __launch_bounds__(256) void fill_csr_kernel(const int* __restrict__ src,
    const int* __restrict__ dst, const int* __restrict__ partials,
    int* __restrict__ cursor, int* __restrict__ col) {
  int exc = wave_partials_excl(partials);
  int e = blockIdx.x * 256 + threadIdx.x;
  if (e < N_EDGES) {
    int d = dst[e];
    int p = atomicAdd(&cursor[d], 1);
    int pre = __shfl(exc, d >> 10, 64);
    col[p + pre] = src[e];
  }
}

// ---- aggregation: h = t(x[node]) + sum t(x[src]); t = optional prev-layer bn-relu ----
template <bool TRANS>
__global__ __launch_bounds__(256) void agg_kernel(const __half* __restrict__ xh,
    const int* __restrict__ offsets, const int* __restrict__ partials,
    const int* __restrict__ col,
    const float* __restrict__ scale, const float* __restrict__ shift,
    __half* __restrict__ h) {
  int node = blockIdx.x * 4 + (threadIdx.x >> 6);
  int lane = threadIdx.x & 63;
  int exc = wave_partials_excl(partials);
  float2 scl, shl;
  if (TRANS) {
    scl = ((const float2*)scale)[lane];
    shl = ((const float2*)shift)[lane];
  }
  const __half2* x2 = (const __half2*)xh;
  float2 self = __half22float2(x2[(size_t)node * 64 + lane]);
  float2 acc;
  if (TRANS) {
    acc.x = fmaxf(fmaf(self.x, scl.x, shl.x), 0.f);
    acc.y = fmaxf(fmaf(self.y, scl.y, shl.y), 0.f);
  } else {
    acc = self;
  }
  int beg = offsets[node] + __shfl(exc, node >> 10, 64);
  int end = offsets[node + 1] + __shfl(exc, (node + 1) >> 10, 64);
  for (int e = beg; e < end; e += 8) {
    int idx[8];
    bool val[8];
#pragma unroll
    for (int j = 0; j < 8; ++j) {
      val[j] = (e + j) < end;
      idx[j] = val[j] ? (e + j) : e;
    }
    int sidx[8];
#pragma unroll
    for (int j = 0; j < 8; ++j) sidx[j] = col[idx[j]];
    float2 ff[8];
#pragma unroll
    for (int j = 0; j < 8; ++j) ff[j] = __half22float2(x2[(size_t)sidx[j] * 64 + lane]);
#pragma unroll
    for (int j = 0; j < 8; ++j) {
      float2 v = ff[j];
      if (TRANS) {
        v.x = fmaxf(fmaf(v.x, scl.x, shl.x), 0.f);
        v.y = fmaxf(fmaf(v.y, scl.y, shl.y), 0.f);
      }
      if (val[j]) {
        acc.x += v.x;
        acc.y += v.y;
      }
    }
  }
  ((__half2*)h)[(size_t)node * 64 + lane] = __float22half2_rn(acc);
}

// ---- fp16 MFMA GEMM (W hi/lo planes), 64-row tile, 256 thr ----
template <bool FIN_IN>
__global__ __launch_bounds__(256) void gemm_f16_kernel(
    const __half* __restrict__ A, const unsigned short* __restrict__ Wh,
    const unsigned short* __restrict__ Wl, const float* __restrict__ bias,
    const float* __restrict__ ibs, const float* __restrict__ ibq,
    const float* __restrict__ bng, const float* __restrict__ bnb,
    __half* __restrict__ Y, float* __restrict__ obs, float* __restrict__ obq) {
  __shared__ unsigned short AL[64][136];  // fp16 bits; +8 pad
  __shared__ float scL[128], shL[128];
  int t = threadIdx.x;
  int row0 = blockIdx.x * 64;
  int lane = t & 63;
  int wv = t >> 6;

  if (FIN_IN) {
    if (t < 128) {
      float s = 0.f, q = 0.f;
#pragma unroll
      for (int i = 0; i < NBUCKET; ++i) {
        s += ibs[i * 128 + t];
        q += ibq[i * 128 + t];
      }
      float mu = s * (1.0f / N_NODES);
      float var = fmaxf(q * (1.0f / N_NODES) - mu * mu, 0.f);
      float sc = bng[t] * rsqrtf(var + BN_EPS);
      scL[t] = sc;
      shL[t] = fmaf(-mu, sc, bnb[t]);
    }
    __syncthreads();
  }

#pragma unroll
  for (int i = 0; i < 4; ++i) {
    int s = i * 256 + t;
    int r = s >> 4, c8 = s & 15;
    int row = row0 + r;
    short8 v = {0, 0, 0, 0, 0, 0, 0, 0};
    if (row < N_NODES) v = *(const short8*)(A + (size_t)row * D + c8 * 8);
    if (FIN_IN) {
      float4 sc0 = *(const float4*)&scL[c8 * 8];
      float4 sc1 = *(const float4*)&scL[c8 * 8 + 4];
      float4 sh0 = *(const float4*)&shL[c8 * 8];
      float4 sh1 = *(const float4*)&shL[c8 * 8 + 4];
      float scv[8] = {sc0.x, sc0.y, sc0.z, sc0.w, sc1.x, sc1.y, sc1.z, sc1.w};
      float shv[8] = {sh0.x, sh0.y, sh0.z, sh0.w, sh1.x, sh1.y, sh1.z, sh1.w};
      short8 o;
#pragma unroll
      for (int j = 0; j < 8; ++j) {
        float f = fmaxf(fmaf(half_bits_to_f32(v[j]), scv[j], shv[j]), 0.f);
        o[j] = (short)f32_to_half_bits(f);
      }
      v = o;
    }
    *(short8*)&AL[r][c8 * 8] = v;
  }
  __syncthreads();

  f32x4 acch[4][2], accl[4][2];
#pragma unroll
  for (int rt = 0; rt < 4; ++rt)
#pragma unroll
    for (int c = 0; c < 2; ++c) {
      acch[rt][c] = (f32x4){0.f, 0.f, 0.f, 0.f};
      accl[rt][c] = (f32x4){0.f, 0.f, 0.f, 0.f};
    }

  int arow_lo = lane & 15;
  int kgrp = (lane >> 4) * 8;
#pragma unroll
  for (int ks = 0; ks < 4; ++ks) {
    size_t wbase = ((size_t)(ks * 8 + wv * 2) * 64 + lane) * 8;
    half8 wh0 = __builtin_bit_cast(half8, *(const short8*)(Wh + wbase));
    half8 wl0 = __builtin_bit_cast(half8, *(const short8*)(Wl + wbase));
    half8 wh1 = __builtin_bit_cast(half8, *(const short8*)(Wh + wbase + 512));
    half8 wl1 = __builtin_bit_cast(half8, *(const short8*)(Wl + wbase + 512));
#pragma unroll
    for (int rt = 0; rt < 4; ++rt) {
      half8 av = __builtin_bit_cast(half8,
          *(const short8*)&AL[rt * 16 + arow_lo][ks * 32 + kgrp]);
      acch[rt][0] = __builtin_amdgcn_mfma_f32_16x16x32_f16(av, wh0, acch[rt][0], 0, 0, 0);
      accl[rt][0] = __builtin_amdgcn_mfma_f32_16x16x32_f16(av, wl0, accl[rt][0], 0, 0, 0);
      acch[rt][1] = __builtin_amdgcn_mfma_f32_16x16x32_f16(av, wh1, acch[rt][1], 0, 0, 0);
      accl[rt][1] = __builtin_amdgcn_mfma_f32_16x16x32_f16(av, wl1, accl[rt][1], 0, 0, 0);
    }
  }

  __syncthreads();  // reuse AL as fp16 output staging

  int rsub = (lane >> 4) << 2;
  int cl = lane & 15;
  int bkt = (blockIdx.x & (NBUCKET - 1)) * 128;
#pragma unroll
  for (int cti = 0; cti < 2; ++cti) {
    int c = wv * 32 + cti * 16 + cl;
    float b = bias[c];
    float s = 0.f, q = 0.f;
#pragma unroll
    for (int rt = 0; rt < 4; ++rt) {
#pragma unroll
      for (int r = 0; r < 4; ++r) {
        int rl = rt * 16 + rsub + r;
        float y = fmaf(accl[rt][cti][r], WLO_INV, acch[rt][cti][r]) + b;
        ((__half*)&AL[rl][0])[c] = __float2half(y);
        if (row0 + rl < N_NODES) {
          s += y;
          q += y * y;
        }
      }
    }
    s += __shfl_xor(s, 16, 64);
    s += __shfl_xor(s, 32, 64);
    q += __shfl_xor(q, 16, 64);
    q += __shfl_xor(q, 32, 64);
    if (lane < 16) {
      atomicAdd(&obs[bkt + c], s);
      atomicAdd(&obq[bkt + c], q);
    }
  }
  __syncthreads();
#pragma unroll
  for (int i = 0; i < 4; ++i) {
    int s = i * 256 + t;
    int r = s >> 4, c8 = s & 15;
    int row = row0 + r;
    if (row < N_NODES) {
      ushort4 a = *(ushort4*)&AL[r][c8 * 8];
      ushort4 b = *(ushort4*)&AL[r][c8 * 8 + 4];
      *(ushort4*)((unsigned short*)Y + (size_t)row * D + c8 * 8)     = a;
      *(ushort4*)((unsigned short*)Y + (size_t)row * D + c8 * 8 + 4) = b;
    }
  }
}

// ---- BN finalize (layers 0-2): 1 block, reduce NBUCKET x 128 -> scale/shift ----
__global__ __launch_bounds__(128) void finalize_kernel(const float* __restrict__ bs,
    const float* __restrict__ bq, const float* __restrict__ g, const float* __restrict__ b,
    float* __restrict__ scale, float* __restrict__ shift) {
  int c = threadIdx.x;
  float s = 0.f, q = 0.f;
#pragma unroll
  for (int i = 0; i < NBUCKET; ++i) {
    s += bs[i * 128 + c];
    q += bq[i * 128 + c];
  }
  float mu = s * (1.0f / N_NODES);
  float var = fmaxf(q * (1.0f / N_NODES) - mu * mu, 0.f);
  float sc = g[c] * rsqrtf(var + BN_EPS);
  scale[c] = sc;
  shift[c] = fmaf(-mu, sc, b[c]);
}

// ---- pooling with inlined layer-3 bn finalize ----
__device__ __forceinline__ int lower_bound_batch(const int* __restrict__ batch, int key) {
  int lo = 0, hi = N_NODES;
  while (lo < hi) {
    int mid = (lo + hi) >> 1;
    if (batch[mid] < key) lo = mid + 1; else hi = mid;
  }
  return lo;
}

__global__ __launch_bounds__(256) void pool_kernel(const __half* __restrict__ x,
    const int* __restrict__ batch, const float* __restrict__ bs,
    const float* __restrict__ bq, const float* __restrict__ g,
    const float* __restrict__ b, float* __restrict__ pp, float* __restrict__ gcnt) {
  int gr = blockIdx.x, chunk = blockIdx.y;
  int f = threadIdx.x & 127, sub = threadIdx.x >> 7;
  // inline finalize for col f
  float s0 = 0.f, q0 = 0.f;
#pragma unroll
  for (int i = 0; i < NBUCKET; ++i) {
    s0 += bs[i * 128 + f];
    q0 += bq[i * 128 + f];
  }
  float mu = s0 * (1.0f / N_NODES);
  float var = fmaxf(q0 * (1.0f / N_NODES) - mu * mu, 0.f);
  float sc = g[f] * rsqrtf(var + BN_EPS);
  float sh = fmaf(-mu, sc, b[f]);

  int lo = lower_bound_batch(batch, gr);
  int hi = lower_bound_batch(batch, gr + 1);
  int cnt = hi - lo;
  int per = (cnt + 7) >> 3;
  int s = lo + chunk * per;
  int e = min(s + per, hi);
  float acc = 0.f;
  for (int n = s + sub; n < e; n += 2)
    acc += fmaxf(fmaf(__half2float(x[(size_t)n * 128 + f]), sc, sh), 0.f);
  __shared__ float red[2][128];
  red[sub][f] = acc;
  __syncthreads();
  if (sub == 0) pp[((size_t)gr * 8 + chunk) * 128 + f] = red[0][f] + red[1][f];
  if (threadIdx.x == 0 && chunk == 0) gcnt[gr] = (float)cnt;
}

// ---------------- final MLP: relu(pooled/cnt @ W1 + b1) @ W2 + b2 ----------------
__global__ __launch_bounds__(256) void mlp_kernel(const float* __restrict__ pp,
    const float* __restrict__ gcnt, const float* __restrict__ w1, const float* __restrict__ b1,
    const float* __restrict__ w2, const float* __restrict__ b2, float* __restrict__ out) {
  int g = blockIdx.x, t = threadIdx.x;
  __shared__ float p[128];
  __shared__ float hbuf[256];
  if (t < 128) {
    float s = 0.f;
#pragma unroll
    for (int c = 0; c < 8; ++c) s += pp[((size_t)g * 8 + c) * 128 + t];
    p[t] = s / fmaxf(gcnt[g], 1.0f);
  }
  __syncthreads();
  float acc = b1[t];
  for (int k = 0; k < 128; ++k) acc = fmaf(p[k], w1[k * 256 + t], acc);
  hbuf[t] = fmaxf(acc, 0.f);
  __syncthreads();
  if (t < 10) {
    float o = b2[t];
    for (int k = 0; k < 256; ++k) o = fmaf(hbuf[k], w2[k * 10 + t], o);
    out[g * 10 + t] = o;
  }
}

// ---------------- launch ----------------
extern "C" void kernel_launch(void* const* d_in, const int* in_sizes, int n_in,
                              void* d_out, int out_size, void* d_ws, size_t ws_size,
                              hipStream_t stream) {
  const int* x_node = (const int*)d_in[0];
  const int* eidx = (const int*)d_in[1];
  const int* batch = (const int*)d_in[2];
  const float* emb = (const float*)d_in[3];
  const float* cw1 = (const float*)d_in[4];
  const float* cb1 = (const float*)d_in[5];
  const float* bn1g = (const float*)d_in[6];
  const float* bn1b = (const float*)d_in[7];
  const float* cw2 = (const float*)d_in[8];
  const float* cb2 = (const float*)d_in[9];
  const float* bn2g = (const float*)d_in[10];
  const float* bn2b = (const float*)d_in[11];
  const float* l1w = (const float*)d_in[12];
  const float* l1b = (const float*)d_in[13];
  const float* l2w = (const float*)d_in[14];
  const float* l2b = (const float*)d_in[15];
  float* out = (float*)d_out;

  char* ws = (char*)d_ws;
  size_t off = 0;
  auto carve = [&](size_t bytes) -> void* {
    void* p = ws + off;
    off += (bytes + 255) & ~(size_t)255;
    return p;
  };
  __half* xh   = (__half*)carve((size_t)N_NODES * D * 2);  // embed output
  __half* abuf = (__half*)carve((size_t)N_NODES * D * 2);  // agg output
  __half* ybuf = (__half*)carve((size_t)N_NODES * D * 2);  // gemm1 raw z1
  __half* zbuf = (__half*)carve((size_t)N_NODES * D * 2);  // gemm2 raw z2
  int* counts = (int*)carve((size_t)N_NODES * 4);
  int* offsets = (int*)carve((size_t)(N_NODES + 1) * 4);
  int* cursor = (int*)carve((size_t)N_NODES * 4);
  int* col = (int*)carve((size_t)N_EDGES * 4);
  int* partials = (int*)carve(64 * 4);
  float* buckets = (float*)carve((size_t)16 * NBUCKET * 128 * 4);
  float* scaleb = (float*)carve(4 * 128 * 4);   // bn2 scale, layers 0-2 used
  float* shiftb = (float*)carve(4 * 128 * 4);
  float* pp = (float*)carve(64 * 8 * 128 * 4);
  float* gcnt = (float*)carve(64 * 4);
  unsigned short* Whb = (unsigned short*)carve((size_t)8 * D * D * 2);
  unsigned short* Wlb = (unsigned short*)carve((size_t)8 * D * D * 2);
  (void)ws_size;
  (void)in_sizes;
  (void)n_in;
  (void)out_size;

  const int* srcp = eidx;
  const int* dstp = eidx + N_EDGES;

  setup_kernel<<<EMB_NB + ZERO_NB + RPK_NB, 256, 0, stream>>>(
      x_node, emb, xh, counts, buckets, cw1, cw2, Whb, Wlb);
  count_kernel<<<(N_EDGES + 255) / 256, 256, 0, stream>>>(dstp, counts);
  scan_block_kernel<<<SCAN_NB, 256, 0, stream>>>(counts, offsets, cursor, partials);
  fill_csr_kernel<<<(N_EDGES + 255) / 256, 256, 0, stream>>>(srcp, dstp, partials,
                                                             cursor, col);

  const size_t BSZ = (size_t)NBUCKET * 128;
  for (int l = 0; l < N_LAYERS; ++l) {
    float* b1s = buckets + (l * 4 + 0) * BSZ;
    float* b1q = buckets + (l * 4 + 1) * BSZ;
    float* b2s = buckets + (l * 4 + 2) * BSZ;
    float* b2q = buckets + (l * 4 + 3) * BSZ;
    float* sc2 = scaleb + l * 128;
    float* sh2 = shiftb + l * 128;
    const float* scp = scaleb + (l - 1) * 128;  // prev layer bn2
    const float* shp = shiftb + (l - 1) * 128;
    const unsigned short* W1h = Whb + (size_t)(l * 2) * D * D;
    const unsigned short* W1l = Wlb + (size_t)(l * 2) * D * D;
    const unsigned short* W2h = Whb + (size_t)(l * 2 + 1) * D * D;
    const unsigned short* W2l = Wlb + (size_t)(l * 2 + 1) * D * D;

    if (l == 0)
      agg_kernel<false><<<12500, 256, 0, stream>>>(xh, offsets, partials, col,
                                                   nullptr, nullptr, abuf);
    else
      agg_kernel<true><<<12500, 256, 0, stream>>>(zbuf, offsets, partials, col,
                                                  scp, shp, abuf);
    gemm_f16_kernel<false><<<GB, 256, 0, stream>>>(abuf, W1h, W1l, cb1 + l * D,
        nullptr, nullptr, nullptr, nullptr, ybuf, b1s, b1q);
    gemm_f16_kernel<true><<<GB, 256, 0, stream>>>(ybuf, W2h, W2l, cb2 + l * D,
        b1s, b1q, bn1g + l * D, bn1b + l * D, zbuf, b2s, b2q);
    if (l < N_LAYERS - 1)
      finalize_kernel<<<1, 128, 0, stream>>>(b2s, b2q, bn2g + l * D, bn2b + l * D,
                                             sc2, sh2);
  }

  pool_kernel<<<dim3(64, 8), 256, 0, stream>>>(zbuf, batch,
      buckets + (3 * 4 + 2) * BSZ, buckets + (3 * 4 + 3) * BSZ,
      bn2g + 3 * D, bn2b + 3 * D, pp, gcnt);
  mlp_kernel<<<64, 256, 0, stream>>>(pp, gcnt, l1w, l1b, l2w, l2b, out);
}

// Round 14
// 328.418 us; speedup vs baseline: 1.0280x; 1.0280x over previous
//
#include <hip/hip_runtime.h>
#include <hip/hip_fp16.h>

#define N_NODES 50000
#define N_EDGES 600000
#define N_GRAPHS 64
#define N_LAYERS 4
#define D 128
#define BN_EPS 1e-5f

#define SCAN_NB 49   // ceil(50000/1024)
#define GB 782       // gemm grid (ceil(50000/64))
#define NBUCKET 32
#define EB 586       // edge-batch grid: 600000 / (256*4) = 585.9

// setup mega-kernel block ranges
#define EMB_NB 6250
#define ZERO_NB 14
#define RPK_NB 8

typedef __attribute__((ext_vector_type(8))) short short8;
typedef __attribute__((ext_vector_type(8))) _Float16 half8;
typedef __attribute__((ext_vector_type(4))) float f32x4;

#define WLO_SCALE 2048.0f
#define WLO_INV (1.0f / 2048.0f)

__device__ __forceinline__ float half_bits_to_f32(short b) {
  union { unsigned short u; __half h; } cv;
  cv.u = (unsigned short)b;
  return __half2float(cv.h);
}
__device__ __forceinline__ unsigned short f32_to_half_bits(float f) {
  union { __half h; unsigned short u; } cv;
  cv.h = __float2half(f);
  return cv.u;
}

// ---- setup mega-kernel: embed | zero(counts + stat buckets) | W repack ----
__global__ __launch_bounds__(256) void setup_kernel(const int* __restrict__ idx,
    const float* __restrict__ emb, __half* __restrict__ xh,
    int* __restrict__ counts, float* __restrict__ buckets,
    const float* __restrict__ cw1, const float* __restrict__ cw2,
    unsigned short* __restrict__ Wh, unsigned short* __restrict__ Wl) {
  int bb = blockIdx.x;
  int t = threadIdx.x;
  if (bb < EMB_NB) {
    int tid = bb * 256 + t;
    if (tid >= N_NODES * 32) return;
    int n = tid >> 5, c4 = tid & 31;
    int e = idx[n];
    float4 v = ((const float4*)emb)[(size_t)e * 32 + c4];
    __half2 a = __float22half2_rn(make_float2(v.x, v.y));
    __half2 b = __float22half2_rn(make_float2(v.z, v.w));
    ((__half2*)xh)[(size_t)tid * 2] = a;
    ((__half2*)xh)[(size_t)tid * 2 + 1] = b;
  } else if (bb < EMB_NB + ZERO_NB) {
    int tid = (bb - EMB_NB) * 256 + t;
    for (int i = tid; i < N_NODES; i += ZERO_NB * 256) counts[i] = 0;
    for (int i = tid; i < 16 * NBUCKET * 128; i += ZERO_NB * 256) buckets[i] = 0.f;
  } else {
    int b = bb - (EMB_NB + ZERO_NB);  // 0..7 = l*2 + which
    int l = b >> 1, which = b & 1;
    const float* Wm = (which ? cw2 : cw1) + (size_t)l * D * D;
    unsigned short* outh = Wh + (size_t)b * D * D;
    unsigned short* outl = Wl + (size_t)b * D * D;
    for (int T = t; T < 2048; T += 256) {
      int ks = T >> 9, ct = (T >> 6) & 7, lane = T & 63;
      int kbase = ks * 32 + ((lane >> 4) << 3);
      int c = ct * 16 + (lane & 15);
      unsigned short hs[8], ls[8];
#pragma unroll
      for (int e = 0; e < 8; ++e) {
        float v = Wm[(size_t)(kbase + e) * D + c];
        __half hh = __float2half_rn(v);
        float rem = v - __half2float(hh);
        __half hl = __float2half_rn(rem * WLO_SCALE);
        union { __half h; unsigned short u; } c1, c2;
        c1.h = hh; c2.h = hl;
        hs[e] = c1.u;
        ls[e] = c2.u;
      }
      *(ushort4*)(outh + (size_t)T * 8)     = *(ushort4*)&hs[0];
      *(ushort4*)(outh + (size_t)T * 8 + 4) = *(ushort4*)&hs[4];
      *(ushort4*)(outl + (size_t)T * 8)     = *(ushort4*)&ls[0];
      *(ushort4*)(outl + (size_t)T * 8 + 4) = *(ushort4*)&ls[4];
    }
  }
}

// ---------------- CSR build (4 edges/thread for MLP) ----------------
__global__ __launch_bounds__(256) void count_kernel(const int* __restrict__ dst,
    int* __restrict__ counts) {
  int i = blockIdx.x * 256 + threadIdx.x;  // quad index
  if (i * 4 >= N_EDGES) return;
  int4 d = ((const int4*)dst)[i];
  atomicAdd(&counts[d.x], 1);
  atomicAdd(&counts[d.y], 1);
  atomicAdd(&counts[d.z], 1);
  atomicAdd(&counts[d.w], 1);
}

__global__ __launch_bounds__(256) void scan_block_kernel(const int* __restrict__ counts,
    int* __restrict__ offsets, int* __restrict__ partials) {
  __shared__ int s[256];
  int t = threadIdx.x;
  int base = blockIdx.x * 1024 + t * 4;
  int v[4];
#pragma unroll
  for (int i = 0; i < 4; ++i) v[i] = (base + i < N_NODES) ? counts[base + i] : 0;
  int tsum = v[0] + v[1] + v[2] + v[3];
  s[t] = tsum;
  __syncthreads();
  for (int off = 1; off < 256; off <<= 1) {
    int add = (t >= off) ? s[t - off] : 0;
    __syncthreads();
    s[t] += add;
    __syncthreads();
  }
  int run = s[t] - tsum;  // exclusive within block
#pragma unroll
  for (int i = 0; i < 4; ++i) {
    if (base + i < N_NODES) offsets[base + i] = run;
    run += v[i];
  }
  if (t == 255) partials[blockIdx.x] = s[255];
}

// add_offsets with inline scan of the 49 block partials
__global__ __launch_bounds__(256) void add_offsets_kernel(int* __restrict__ offsets,
    const int* __restrict__ partials, int* __restrict__ cursor) {
  __shared__ int pre[SCAN_NB];
  int t = threadIdx.x;
  if (t < SCAN_NB) pre[t] = partials[t];
  __syncthreads();
  if (t == 0) {
    int run = 0;
    for (int b = 0; b < SCAN_NB; ++b) { int v = pre[b]; pre[b] = run; run += v; }
  }
  __syncthreads();
  int i = blockIdx.x * 256 + t;
  if (i < N_NODES) {
    int o = offsets[i] + pre[i >> 10];
    offsets[i] = o;
    cursor[i] = o;
  }
  if (blockIdx.x == 0 && t == 0) offsets[N_NODES] = N_EDGES;
}

__global__ __launch_bounds__(256) void fill_csr_kernel(const int* __restrict__ src,
    const int* __restrict__ dst, int* __restrict__ cursor, int* __restrict__ col) {
  int i = blockIdx.x * 256 + threadIdx.x;  // quad index
  if (i * 4 >= N_EDGES) return;
  int4 d = ((const int4*)dst)[i];
  int4 s = ((const int4*)src)[i];
  int p0 = atomicAdd(&cursor[d.x], 1);
  int p1 = atomicAdd(&cursor[d.y], 1);
  int p2 = atomicAdd(&cursor[d.z], 1);
  int p3 = atomicAdd(&cursor[d.w], 1);
  col[p0] = s.x;
  col[p1] = s.y;
  col[p2] = s.z;
  col[p3] = s.w;
}

// ---- aggregation: h = t(x[node]) + sum t(x[src]); t = optional prev-layer bn-relu ----
template <bool TRANS>
__global__ __launch_bounds__(256) void agg_kernel(const __half* __restrict__ xh,
    const int* __restrict__ offsets, const int* __restrict__ col,
    const float* __restrict__ scale, const float* __restrict__ shift,
    __half* __restrict__ h) {
  int node = blockIdx.x * 4 + (threadIdx.x >> 6);
  int lane = threadIdx.x & 63;
  float2 scl, shl;
  if (TRANS) {
    scl = ((const float2*)scale)[lane];
    shl = ((const float2*)shift)[lane];
  }
  const __half2* x2 = (const __half2*)xh;
  float2 self = __half22float2(x2[(size_t)node * 64 + lane]);
  float2 acc;
  if (TRANS) {
    acc.x = fmaxf(fmaf(self.x, scl.x, shl.x), 0.f);
    acc.y = fmaxf(fmaf(self.y, scl.y, shl.y), 0.f);
  } else {
    acc = self;
  }
  int beg = offsets[node], end = offsets[node + 1];
  for (int e = beg; e < end; e += 8) {
    int idx[8];
    bool val[8];
#pragma unroll
    for (int j = 0; j < 8; ++j) {
      val[j] = (e + j) < end;
      idx[j] = val[j] ? (e + j) : e;
    }
    int sidx[8];
#pragma unroll
    for (int j = 0; j < 8; ++j) sidx[j] = col[idx[j]];
    float2 ff[8];
#pragma unroll
    for (int j = 0; j < 8; ++j) ff[j] = __half22float2(x2[(size_t)sidx[j] * 64 + lane]);
#pragma unroll
    for (int j = 0; j < 8; ++j) {
      float2 v = ff[j];
      if (TRANS) {
        v.x = fmaxf(fmaf(v.x, scl.x, shl.x), 0.f);
        v.y = fmaxf(fmaf(v.y, scl.y, shl.y), 0.f);
      }
      if (val[j]) {
        acc.x += v.x;
        acc.y += v.y;
      }
    }
  }
  ((__half2*)h)[(size_t)node * 64 + lane] = __float22half2_rn(acc);
}

// ---- fp16 MFMA GEMM (W hi/lo planes), 64-row tile, 256 thr ----
template <bool FIN_IN>
__global__ __launch_bounds__(256) void gemm_f16_kernel(
    const __half* __restrict__ A, const unsigned short* __restrict__ Wh,
    const unsigned short* __restrict__ Wl, const float* __restrict__ bias,
    const float* __restrict__ ibs, const float* __restrict__ ibq,
    const float* __restrict__ bng, const float* __restrict__ bnb,
    __half* __restrict__ Y, float* __restrict__ obs, float* __restrict__ obq) {
  __shared__ unsigned short AL[64][136];  // fp16 bits; +8 pad
  __shared__ float scL[128], shL[128];
  int t = threadIdx.x;
  int row0 = blockIdx.x * 64;
  int lane = t & 63;
  int wv = t >> 6;

  if (FIN_IN) {
    if (t < 128) {
      float s = 0.f, q = 0.f;
#pragma unroll
      for (int i = 0; i < NBUCKET; ++i) {
        s += ibs[i * 128 + t];
        q += ibq[i * 128 + t];
      }
      float mu = s * (1.0f / N_NODES);
      float var = fmaxf(q * (1.0f / N_NODES) - mu * mu, 0.f);
      float sc = bng[t] * rsqrtf(var + BN_EPS);
      scL[t] = sc;
      shL[t] = fmaf(-mu, sc, bnb[t]);
    }
    __syncthreads();
  }

#pragma unroll
  for (int i = 0; i < 4; ++i) {
    int s = i * 256 + t;
    int r = s >> 4, c8 = s & 15;
    int row = row0 + r;
    short8 v = {0, 0, 0, 0, 0, 0, 0, 0};
    if (row < N_NODES) v = *(const short8*)(A + (size_t)row * D + c8 * 8);
    if (FIN_IN) {
      float4 sc0 = *(const float4*)&scL[c8 * 8];
      float4 sc1 = *(const float4*)&scL[c8 * 8 + 4];
      float4 sh0 = *(const float4*)&shL[c8 * 8];
      float4 sh1 = *(const float4*)&shL[c8 * 8 + 4];
      float scv[8] = {sc0.x, sc0.y, sc0.z, sc0.w, sc1.x, sc1.y, sc1.z, sc1.w};
      float shv[8] = {sh0.x, sh0.y, sh0.z, sh0.w, sh1.x, sh1.y, sh1.z, sh1.w};
      short8 o;
#pragma unroll
      for (int j = 0; j < 8; ++j) {
        float f = fmaxf(fmaf(half_bits_to_f32(v[j]), scv[j], shv[j]), 0.f);
        o[j] = (short)f32_to_half_bits(f);
      }
      v = o;
    }
    *(short8*)&AL[r][c8 * 8] = v;
  }
  __syncthreads();

  f32x4 acch[4][2], accl[4][2];
#pragma unroll
  for (int rt = 0; rt < 4; ++rt)
#pragma unroll
    for (int c = 0; c < 2; ++c) {
      acch[rt][c] = (f32x4){0.f, 0.f, 0.f, 0.f};
      accl[rt][c] = (f32x4){0.f, 0.f, 0.f, 0.f};
    }

  int arow_lo = lane & 15;
  int kgrp = (lane >> 4) * 8;
#pragma unroll
  for (int ks = 0; ks < 4; ++ks) {
    size_t wbase = ((size_t)(ks * 8 + wv * 2) * 64 + lane) * 8;
    half8 wh0 = __builtin_bit_cast(half8, *(const short8*)(Wh + wbase));
    half8 wl0 = __builtin_bit_cast(half8, *(const short8*)(Wl + wbase));
    half8 wh1 = __builtin_bit_cast(half8, *(const short8*)(Wh + wbase + 512));
    half8 wl1 = __builtin_bit_cast(half8, *(const short8*)(Wl + wbase + 512));
#pragma unroll
    for (int rt = 0; rt < 4; ++rt) {
      half8 av = __builtin_bit_cast(half8,
          *(const short8*)&AL[rt * 16 + arow_lo][ks * 32 + kgrp]);
      acch[rt][0] = __builtin_amdgcn_mfma_f32_16x16x32_f16(av, wh0, acch[rt][0], 0, 0, 0);
      accl[rt][0] = __builtin_amdgcn_mfma_f32_16x16x32_f16(av, wl0, accl[rt][0], 0, 0, 0);
      acch[rt][1] = __builtin_amdgcn_mfma_f32_16x16x32_f16(av, wh1, acch[rt][1], 0, 0, 0);
      accl[rt][1] = __builtin_amdgcn_mfma_f32_16x16x32_f16(av, wl1, accl[rt][1], 0, 0, 0);
    }
  }

  __syncthreads();  // reuse AL as fp16 output staging

  int rsub = (lane >> 4) << 2;
  int cl = lane & 15;
  int bkt = (blockIdx.x & (NBUCKET - 1)) * 128;
#pragma unroll
  for (int cti = 0; cti < 2; ++cti) {
    int c = wv * 32 + cti * 16 + cl;
    float b = bias[c];
    float s = 0.f, q = 0.f;
#pragma unroll
    for (int rt = 0; rt < 4; ++rt) {
#pragma unroll
      for (int r = 0; r < 4; ++r) {
        int rl = rt * 16 + rsub + r;
        float y = fmaf(accl[rt][cti][r], WLO_INV, acch[rt][cti][r]) + b;
        ((__half*)&AL[rl][0])[c] = __float2half(y);
        if (row0 + rl < N_NODES) {
          s += y;
          q += y * y;
        }
      }
    }
    s += __shfl_xor(s, 16, 64);
    s += __shfl_xor(s, 32, 64);
    q += __shfl_xor(q, 16, 64);
    q += __shfl_xor(q, 32, 64);
    if (lane < 16) {
      atomicAdd(&obs[bkt + c], s);
      atomicAdd(&obq[bkt + c], q);
    }
  }
  __syncthreads();
#pragma unroll
  for (int i = 0; i < 4; ++i) {
    int s = i * 256 + t;
    int r = s >> 4, c8 = s & 15;
    int row = row0 + r;
    if (row < N_NODES) {
      ushort4 a = *(ushort4*)&AL[r][c8 * 8];
      ushort4 b = *(ushort4*)&AL[r][c8 * 8 + 4];
      *(ushort4*)((unsigned short*)Y + (size_t)row * D + c8 * 8)     = a;
      *(ushort4*)((unsigned short*)Y + (size_t)row * D + c8 * 8 + 4) = b;
    }
  }
}

// ---- BN finalize (layers 0-2): 1 block, reduce NBUCKET x 128 -> scale/shift ----
__global__ __launch_bounds__(128) void finalize_kernel(const float* __restrict__ bs,
    const float* __restrict__ bq, const float* __restrict__ g, const float* __restrict__ b,
    float* __restrict__ scale, float* __restrict__ shift) {
  int c = threadIdx.x;
  float s = 0.f, q = 0.f;
#pragma unroll
  for (int i = 0; i < NBUCKET; ++i) {
    s += bs[i * 128 + c];
    q += bq[i * 128 + c];
  }
  float mu = s * (1.0f / N_NODES);
  float var = fmaxf(q * (1.0f / N_NODES) - mu * mu, 0.f);
  float sc = g[c] * rsqrtf(var + BN_EPS);
  scale[c] = sc;
  shift[c] = fmaf(-mu, sc, b[c]);
}

// ---- pooling with inlined layer-3 bn finalize ----
__device__ __forceinline__ int lower_bound_batch(const int* __restrict__ batch, int key) {
  int lo = 0, hi = N_NODES;
  while (lo < hi) {
    int mid = (lo + hi) >> 1;
    if (batch[mid] < key) lo = mid + 1; else hi = mid;
  }
  return lo;
}

__global__ __launch_bounds__(256) void pool_kernel(const __half* __restrict__ x,
    const int* __restrict__ batch, const float* __restrict__ bs,
    const float* __restrict__ bq, const float* __restrict__ g,
    const float* __restrict__ b, float* __restrict__ pp, float* __restrict__ gcnt) {
  int gr = blockIdx.x, chunk = blockIdx.y;
  int f = threadIdx.x & 127, sub = threadIdx.x >> 7;
  float s0 = 0.f, q0 = 0.f;
#pragma unroll
  for (int i = 0; i < NBUCKET; ++i) {
    s0 += bs[i * 128 + f];
    q0 += bq[i * 128 + f];
  }
  float mu = s0 * (1.0f / N_NODES);
  float var = fmaxf(q0 * (1.0f / N_NODES) - mu * mu, 0.f);
  float sc = g[f] * rsqrtf(var + BN_EPS);
  float sh = fmaf(-mu, sc, b[f]);

  int lo = lower_bound_batch(batch, gr);
  int hi = lower_bound_batch(batch, gr + 1);
  int cnt = hi - lo;
  int per = (cnt + 7) >> 3;
  int s = lo + chunk * per;
  int e = min(s + per, hi);
  float acc = 0.f;
  for (int n = s + sub; n < e; n += 2)
    acc += fmaxf(fmaf(__half2float(x[(size_t)n * 128 + f]), sc, sh), 0.f);
  __shared__ float red[2][128];
  red[sub][f] = acc;
  __syncthreads();
  if (sub == 0) pp[((size_t)gr * 8 + chunk) * 128 + f] = red[0][f] + red[1][f];
  if (threadIdx.x == 0 && chunk == 0) gcnt[gr] = (float)cnt;
}

// ---------------- final MLP: relu(pooled/cnt @ W1 + b1) @ W2 + b2 ----------------
__global__ __launch_bounds__(256) void mlp_kernel(const float* __restrict__ pp,
    const float* __restrict__ gcnt, const float* __restrict__ w1, const float* __restrict__ b1,
    const float* __restrict__ w2, const float* __restrict__ b2, float* __restrict__ out) {
  int g = blockIdx.x, t = threadIdx.x;
  __shared__ float p[128];
  __shared__ float hbuf[256];
  if (t < 128) {
    float s = 0.f;
#pragma unroll
    for (int c = 0; c < 8; ++c) s += pp[((size_t)g * 8 + c) * 128 + t];
    p[t] = s / fmaxf(gcnt[g], 1.0f);
  }
  __syncthreads();
  float acc = b1[t];
  for (int k = 0; k < 128; ++k) acc = fmaf(p[k], w1[k * 256 + t], acc);
  hbuf[t] = fmaxf(acc, 0.f);
  __syncthreads();
  if (t < 10) {
    float o = b2[t];
    for (int k = 0; k < 256; ++k) o = fmaf(hbuf[k], w2[k * 10 + t], o);
    out[g * 10 + t] = o;
  }
}

// ---------------- launch ----------------
extern "C" void kernel_launch(void* const* d_in, const int* in_sizes, int n_in,
                              void* d_out, int out_size, void* d_ws, size_t ws_size,
                              hipStream_t stream) {
  const int* x_node = (const int*)d_in[0];
  const int* eidx = (const int*)d_in[1];
  const int* batch = (const int*)d_in[2];
  const float* emb = (const float*)d_in[3];
  const float* cw1 = (const float*)d_in[4];
  const float* cb1 = (const float*)d_in[5];
  const float* bn1g = (const float*)d_in[6];
  const float* bn1b = (const float*)d_in[7];
  const float* cw2 = (const float*)d_in[8];
  const float* cb2 = (const float*)d_in[9];
  const float* bn2g = (const float*)d_in[10];
  const float* bn2b = (const float*)d_in[11];
  const float* l1w = (const float*)d_in[12];
  const float* l1b = (const float*)d_in[13];
  const float* l2w = (const float*)d_in[14];
  const float* l2b = (const float*)d_in[15];
  float* out = (float*)d_out;

  char* ws = (char*)d_ws;
  size_t off = 0;
  auto carve = [&](size_t bytes) -> void* {
    void* p = ws + off;
    off += (bytes + 255) & ~(size_t)255;
    return p;
  };
  __half* xh   = (__half*)carve((size_t)N_NODES * D * 2);  // embed output
  __half* abuf = (__half*)carve((size_t)N_NODES * D * 2);  // agg output
  __half* ybuf = (__half*)carve((size_t)N_NODES * D * 2);  // gemm1 raw z1
  __half* zbuf = (__half*)carve((size_t)N_NODES * D * 2);  // gemm2 raw z2
  int* counts = (int*)carve((size_t)N_NODES * 4);
  int* offsets = (int*)carve((size_t)(N_NODES + 1) * 4);
  int* cursor = (int*)carve((size_t)N_NODES * 4);
  int* col = (int*)carve((size_t)N_EDGES * 4);
  int* partials = (int*)carve(64 * 4);
  float* buckets = (float*)carve((size_t)16 * NBUCKET * 128 * 4);
  float* scaleb = (float*)carve(4 * 128 * 4);   // bn2 scale, layers 0-2 used
  float* shiftb = (float*)carve(4 * 128 * 4);
  float* pp = (float*)carve(64 * 8 * 128 * 4);
  float* gcnt = (float*)carve(64 * 4);
  unsigned short* Whb = (unsigned short*)carve((size_t)8 * D * D * 2);
  unsigned short* Wlb = (unsigned short*)carve((size_t)8 * D * D * 2);
  (void)ws_size;
  (void)in_sizes;
  (void)n_in;
  (void)out_size;

  const int* srcp = eidx;
  const int* dstp = eidx + N_EDGES;

  setup_kernel<<<EMB_NB + ZERO_NB + RPK_NB, 256, 0, stream>>>(
      x_node, emb, xh, counts, buckets, cw1, cw2, Whb, Wlb);
  count_kernel<<<EB, 256, 0, stream>>>(dstp, counts);
  scan_block_kernel<<<SCAN_NB, 256, 0, stream>>>(counts, offsets, partials);
  add_offsets_kernel<<<(N_NODES + 255) / 256, 256, 0, stream>>>(offsets, partials, cursor);
  fill_csr_kernel<<<EB, 256, 0, stream>>>(srcp, dstp, cursor, col);

  const size_t BSZ = (size_t)NBUCKET * 128;
  for (int l = 0; l < N_LAYERS; ++l) {
    float* b1s = buckets + (l * 4 + 0) * BSZ;
    float* b1q = buckets + (l * 4 + 1) * BSZ;
    float* b2s = buckets + (l * 4 + 2) * BSZ;
    float* b2q = buckets + (l * 4 + 3) * BSZ;
    float* sc2 = scaleb + l * 128;
    float* sh2 = shiftb + l * 128;
    const float* scp = scaleb + (l - 1) * 128;  // prev layer bn2
    const float* shp = shiftb + (l - 1) * 128;
    const unsigned short* W1h = Whb + (size_t)(l * 2) * D * D;
    const unsigned short* W1l = Wlb + (size_t)(l * 2) * D * D;
    const unsigned short* W2h = Whb + (size_t)(l * 2 + 1) * D * D;
    const unsigned short* W2l = Wlb + (size_t)(l * 2 + 1) * D * D;

    if (l == 0)
      agg_kernel<false><<<12500, 256, 0, stream>>>(xh, offsets, col, nullptr, nullptr, abuf);
    else
      agg_kernel<true><<<12500, 256, 0, stream>>>(zbuf, offsets, col, scp, shp, abuf);
    gemm_f16_kernel<false><<<GB, 256, 0, stream>>>(abuf, W1h, W1l, cb1 + l * D,
        nullptr, nullptr, nullptr, nullptr, ybuf, b1s, b1q);
    gemm_f16_kernel<true><<<GB, 256, 0, stream>>>(ybuf, W2h, W2l, cb2 + l * D,
        b1s, b1q, bn1g + l * D, bn1b + l * D, zbuf, b2s, b2q);
    if (l < N_LAYERS - 1)
      finalize_kernel<<<1, 128, 0, stream>>>(b2s, b2q, bn2g + l * D, bn2b + l * D,
                                             sc2, sh2);
  }

  pool_kernel<<<dim3(64, 8), 256, 0, stream>>>(zbuf, batch,
      buckets + (3 * 4 + 2) * BSZ, buckets + (3 * 4 + 3) * BSZ,
      bn2g + 3 * D, bn2b + 3 * D, pp, gcnt);
  mlp_kernel<<<64, 256, 0, stream>>>(pp, gcnt, l1w, l1b, l2w, l2b, out);
}

// Round 15
// 298.365 us; speedup vs baseline: 1.1315x; 1.1007x over previous
//
#include <hip/hip_runtime.h>
#include <hip/hip_fp16.h>

#define N_NODES 50000
#define N_EDGES 600000
#define N_GRAPHS 64
#define N_LAYERS 4
#define D 128
#define BN_EPS 1e-5f

#define SCAN_NB 49   // ceil(50000/1024)
#define GB 782       // gemm grid (ceil(50000/64))
#define NBUCKET 32
#define EB 586       // edge-batch grid: 600000 / (256*4)

// setup mega-kernel block ranges
#define EMB_NB 6250
#define ZERO_NB 14
#define RPK_NB 8

typedef __attribute__((ext_vector_type(8))) short short8;
typedef __attribute__((ext_vector_type(8))) _Float16 half8;
typedef __attribute__((ext_vector_type(4))) float f32x4;

__device__ __forceinline__ float half_bits_to_f32(short b) {
  union { unsigned short u; __half h; } cv;
  cv.u = (unsigned short)b;
  return __half2float(cv.h);
}
__device__ __forceinline__ unsigned short f32_to_half_bits(float f) {
  union { __half h; unsigned short u; } cv;
  cv.h = __float2half(f);
  return cv.u;
}

// ---- setup mega-kernel: embed | zero(counts + stat buckets) | W repack ----
__global__ __launch_bounds__(256) void setup_kernel(const int* __restrict__ idx,
    const float* __restrict__ emb, __half* __restrict__ xh,
    int* __restrict__ counts, float* __restrict__ buckets,
    const float* __restrict__ cw1, const float* __restrict__ cw2,
    unsigned short* __restrict__ Wh) {
  int bb = blockIdx.x;
  int t = threadIdx.x;
  if (bb < EMB_NB) {
    int tid = bb * 256 + t;
    if (tid >= N_NODES * 32) return;
    int n = tid >> 5, c4 = tid & 31;
    int e = idx[n];
    float4 v = ((const float4*)emb)[(size_t)e * 32 + c4];
    __half2 a = __float22half2_rn(make_float2(v.x, v.y));
    __half2 b = __float22half2_rn(make_float2(v.z, v.w));
    ((__half2*)xh)[(size_t)tid * 2] = a;
    ((__half2*)xh)[(size_t)tid * 2 + 1] = b;
  } else if (bb < EMB_NB + ZERO_NB) {
    int tid = (bb - EMB_NB) * 256 + t;
    for (int i = tid; i < N_NODES; i += ZERO_NB * 256) counts[i] = 0;
    for (int i = tid; i < 16 * NBUCKET * 128; i += ZERO_NB * 256) buckets[i] = 0.f;
  } else {
    int b = bb - (EMB_NB + ZERO_NB);  // 0..7 = l*2 + which
    int l = b >> 1, which = b & 1;
    const float* Wm = (which ? cw2 : cw1) + (size_t)l * D * D;
    unsigned short* outh = Wh + (size_t)b * D * D;
    for (int T = t; T < 2048; T += 256) {
      int ks = T >> 9, ct = (T >> 6) & 7, lane = T & 63;
      int kbase = ks * 32 + ((lane >> 4) << 3);
      int c = ct * 16 + (lane & 15);
      unsigned short hs[8];
#pragma unroll
      for (int e = 0; e < 8; ++e) {
        float v = Wm[(size_t)(kbase + e) * D + c];
        hs[e] = f32_to_half_bits(v);
      }
      *(ushort4*)(outh + (size_t)T * 8)     = *(ushort4*)&hs[0];
      *(ushort4*)(outh + (size_t)T * 8 + 4) = *(ushort4*)&hs[4];
    }
  }
}

// ---------------- CSR build (4 edges/thread for MLP) ----------------
__global__ __launch_bounds__(256) void count_kernel(const int* __restrict__ dst,
    int* __restrict__ counts) {
  int i = blockIdx.x * 256 + threadIdx.x;  // quad index
  if (i * 4 >= N_EDGES) return;
  int4 d = ((const int4*)dst)[i];
  atomicAdd(&counts[d.x], 1);
  atomicAdd(&counts[d.y], 1);
  atomicAdd(&counts[d.z], 1);
  atomicAdd(&counts[d.w], 1);
}

__global__ __launch_bounds__(256) void scan_block_kernel(const int* __restrict__ counts,
    int* __restrict__ offsets, int* __restrict__ partials) {
  __shared__ int s[256];
  int t = threadIdx.x;
  int base = blockIdx.x * 1024 + t * 4;
  int v[4];
#pragma unroll
  for (int i = 0; i < 4; ++i) v[i] = (base + i < N_NODES) ? counts[base + i] : 0;
  int tsum = v[0] + v[1] + v[2] + v[3];
  s[t] = tsum;
  __syncthreads();
  for (int off = 1; off < 256; off <<= 1) {
    int add = (t >= off) ? s[t - off] : 0;
    __syncthreads();
    s[t] += add;
    __syncthreads();
  }
  int run = s[t] - tsum;  // exclusive within block
#pragma unroll
  for (int i = 0; i < 4; ++i) {
    if (base + i < N_NODES) offsets[base + i] = run;
    run += v[i];
  }
  if (t == 255) partials[blockIdx.x] = s[255];
}

// add_offsets with inline scan of the 49 block partials
__global__ __launch_bounds__(256) void add_offsets_kernel(int* __restrict__ offsets,
    const int* __restrict__ partials, int* __restrict__ cursor) {
  __shared__ int pre[SCAN_NB];
  int t = threadIdx.x;
  if (t < SCAN_NB) pre[t] = partials[t];
  __syncthreads();
  if (t == 0) {
    int run = 0;
    for (int b = 0; b < SCAN_NB; ++b) { int v = pre[b]; pre[b] = run; run += v; }
  }
  __syncthreads();
  int i = blockIdx.x * 256 + t;
  if (i < N_NODES) {
    int o = offsets[i] + pre[i >> 10];
    offsets[i] = o;
    cursor[i] = o;
  }
  if (blockIdx.x == 0 && t == 0) offsets[N_NODES] = N_EDGES;
}

__global__ __launch_bounds__(256) void fill_csr_kernel(const int* __restrict__ src,
    const int* __restrict__ dst, int* __restrict__ cursor, int* __restrict__ col) {
  int i = blockIdx.x * 256 + threadIdx.x;  // quad index
  if (i * 4 >= N_EDGES) return;
  int4 d = ((const int4*)dst)[i];
  int4 s = ((const int4*)src)[i];
  int p0 = atomicAdd(&cursor[d.x], 1);
  int p1 = atomicAdd(&cursor[d.y], 1);
  int p2 = atomicAdd(&cursor[d.z], 1);
  int p3 = atomicAdd(&cursor[d.w], 1);
  col[p0] = s.x;
  col[p1] = s.y;
  col[p2] = s.z;
  col[p3] = s.w;
}

// ---- aggregation: h = t(x[node]) + sum t(x[src]); t = optional prev-layer bn-relu ----
template <bool TRANS>
__global__ __launch_bounds__(256) void agg_kernel(const __half* __restrict__ xh,
    const int* __restrict__ offsets, const int* __restrict__ col,
    const float* __restrict__ scale, const float* __restrict__ shift,
    __half* __restrict__ h) {
  int node = blockIdx.x * 4 + (threadIdx.x >> 6);
  int lane = threadIdx.x & 63;
  float2 scl, shl;
  if (TRANS) {
    scl = ((const float2*)scale)[lane];
    shl = ((const float2*)shift)[lane];
  }
  const __half2* x2 = (const __half2*)xh;
  float2 self = __half22float2(x2[(size_t)node * 64 + lane]);
  float2 acc;
  if (TRANS) {
    acc.x = fmaxf(fmaf(self.x, scl.x, shl.x), 0.f);
    acc.y = fmaxf(fmaf(self.y, scl.y, shl.y), 0.f);
  } else {
    acc = self;
  }
  int beg = offsets[node], end = offsets[node + 1];
  for (int e = beg; e < end; e += 8) {
    int idx[8];
    bool val[8];
#pragma unroll
    for (int j = 0; j < 8; ++j) {
      val[j] = (e + j) < end;
      idx[j] = val[j] ? (e + j) : e;
    }
    int sidx[8];
#pragma unroll
    for (int j = 0; j < 8; ++j) sidx[j] = col[idx[j]];
    float2 ff[8];
#pragma unroll
    for (int j = 0; j < 8; ++j) ff[j] = __half22float2(x2[(size_t)sidx[j] * 64 + lane]);
#pragma unroll
    for (int j = 0; j < 8; ++j) {
      float2 v = ff[j];
      if (TRANS) {
        v.x = fmaxf(fmaf(v.x, scl.x, shl.x), 0.f);
        v.y = fmaxf(fmaf(v.y, scl.y, shl.y), 0.f);
      }
      if (val[j]) {
        acc.x += v.x;
        acc.y += v.y;
      }
    }
  }
  ((__half2*)h)[(size_t)node * 64 + lane] = __float22half2_rn(acc);
}

// ---- fp16 MFMA GEMM (single-plane fp16 W), 64-row tile, 256 thr ----
template <bool FIN_IN>
__global__ __launch_bounds__(256) void gemm_f16_kernel(
    const __half* __restrict__ A, const unsigned short* __restrict__ Wh,
    const float* __restrict__ bias,
    const float* __restrict__ ibs, const float* __restrict__ ibq,
    const float* __restrict__ bng, const float* __restrict__ bnb,
    __half* __restrict__ Y, float* __restrict__ obs, float* __restrict__ obq) {
  __shared__ unsigned short AL[64][136];  // fp16 bits; +8 pad
  __shared__ float scL[128], shL[128];
  int t = threadIdx.x;
  int row0 = blockIdx.x * 64;
  int lane = t & 63;
  int wv = t >> 6;

  if (FIN_IN) {
    if (t < 128) {
      float s = 0.f, q = 0.f;
#pragma unroll
      for (int i = 0; i < NBUCKET; ++i) {
        s += ibs[i * 128 + t];
        q += ibq[i * 128 + t];
      }
      float mu = s * (1.0f / N_NODES);
      float var = fmaxf(q * (1.0f / N_NODES) - mu * mu, 0.f);
      float sc = bng[t] * rsqrtf(var + BN_EPS);
      scL[t] = sc;
      shL[t] = fmaf(-mu, sc, bnb[t]);
    }
    __syncthreads();
  }

#pragma unroll
  for (int i = 0; i < 4; ++i) {
    int s = i * 256 + t;
    int r = s >> 4, c8 = s & 15;
    int row = row0 + r;
    short8 v = {0, 0, 0, 0, 0, 0, 0, 0};
    if (row < N_NODES) v = *(const short8*)(A + (size_t)row * D + c8 * 8);
    if (FIN_IN) {
      float4 sc0 = *(const float4*)&scL[c8 * 8];
      float4 sc1 = *(const float4*)&scL[c8 * 8 + 4];
      float4 sh0 = *(const float4*)&shL[c8 * 8];
      float4 sh1 = *(const float4*)&shL[c8 * 8 + 4];
      float scv[8] = {sc0.x, sc0.y, sc0.z, sc0.w, sc1.x, sc1.y, sc1.z, sc1.w};
      float shv[8] = {sh0.x, sh0.y, sh0.z, sh0.w, sh1.x, sh1.y, sh1.z, sh1.w};
      short8 o;
#pragma unroll
      for (int j = 0; j < 8; ++j) {
        float f = fmaxf(fmaf(half_bits_to_f32(v[j]), scv[j], shv[j]), 0.f);
        o[j] = (short)f32_to_half_bits(f);
      }
      v = o;
    }
    *(short8*)&AL[r][c8 * 8] = v;
  }
  __syncthreads();

  f32x4 acc[4][2];
#pragma unroll
  for (int rt = 0; rt < 4; ++rt)
#pragma unroll
    for (int c = 0; c < 2; ++c) acc[rt][c] = (f32x4){0.f, 0.f, 0.f, 0.f};

  int arow_lo = lane & 15;
  int kgrp = (lane >> 4) * 8;
#pragma unroll
  for (int ks = 0; ks < 4; ++ks) {
    size_t wbase = ((size_t)(ks * 8 + wv * 2) * 64 + lane) * 8;
    half8 wh0 = __builtin_bit_cast(half8, *(const short8*)(Wh + wbase));
    half8 wh1 = __builtin_bit_cast(half8, *(const short8*)(Wh + wbase + 512));
#pragma unroll
    for (int rt = 0; rt < 4; ++rt) {
      half8 av = __builtin_bit_cast(half8,
          *(const short8*)&AL[rt * 16 + arow_lo][ks * 32 + kgrp]);
      acc[rt][0] = __builtin_amdgcn_mfma_f32_16x16x32_f16(av, wh0, acc[rt][0], 0, 0, 0);
      acc[rt][1] = __builtin_amdgcn_mfma_f32_16x16x32_f16(av, wh1, acc[rt][1], 0, 0, 0);
    }
  }

  __syncthreads();  // reuse AL as fp16 output staging

  int rsub = (lane >> 4) << 2;
  int cl = lane & 15;
  int bkt = (blockIdx.x & (NBUCKET - 1)) * 128;
#pragma unroll
  for (int cti = 0; cti < 2; ++cti) {
    int c = wv * 32 + cti * 16 + cl;
    float b = bias[c];
    float s = 0.f, q = 0.f;
#pragma unroll
    for (int rt = 0; rt < 4; ++rt) {
#pragma unroll
      for (int r = 0; r < 4; ++r) {
        int rl = rt * 16 + rsub + r;
        float y = acc[rt][cti][r] + b;
        ((__half*)&AL[rl][0])[c] = __float2half(y);
        if (row0 + rl < N_NODES) {
          s += y;
          q += y * y;
        }
      }
    }
    s += __shfl_xor(s, 16, 64);
    s += __shfl_xor(s, 32, 64);
    q += __shfl_xor(q, 16, 64);
    q += __shfl_xor(q, 32, 64);
    if (lane < 16) {
      atomicAdd(&obs[bkt + c], s);
      atomicAdd(&obq[bkt + c], q);
    }
  }
  __syncthreads();
#pragma unroll
  for (int i = 0; i < 4; ++i) {
    int s = i * 256 + t;
    int r = s >> 4, c8 = s & 15;
    int row = row0 + r;
    if (row < N_NODES) {
      ushort4 a = *(ushort4*)&AL[r][c8 * 8];
      ushort4 b = *(ushort4*)&AL[r][c8 * 8 + 4];
      *(ushort4*)((unsigned short*)Y + (size_t)row * D + c8 * 8)     = a;
      *(ushort4*)((unsigned short*)Y + (size_t)row * D + c8 * 8 + 4) = b;
    }
  }
}

// ---- BN finalize (layers 0-2): 1 block, reduce NBUCKET x 128 -> scale/shift ----
__global__ __launch_bounds__(128) void finalize_kernel(const float* __restrict__ bs,
    const float* __restrict__ bq, const float* __restrict__ g, const float* __restrict__ b,
    float* __restrict__ scale, float* __restrict__ shift) {
  int c = threadIdx.x;
  float s = 0.f, q = 0.f;
#pragma unroll
  for (int i = 0; i < NBUCKET; ++i) {
    s += bs[i * 128 + c];
    q += bq[i * 128 + c];
  }
  float mu = s * (1.0f / N_NODES);
  float var = fmaxf(q * (1.0f / N_NODES) - mu * mu, 0.f);
  float sc = g[c] * rsqrtf(var + BN_EPS);
  scale[c] = sc;
  shift[c] = fmaf(-mu, sc, b[c]);
}

// ---- pooling with inlined layer-3 bn finalize ----
__device__ __forceinline__ int lower_bound_batch(const int* __restrict__ batch, int key) {
  int lo = 0, hi = N_NODES;
  while (lo < hi) {
    int mid = (lo + hi) >> 1;
    if (batch[mid] < key) lo = mid + 1; else hi = mid;
  }
  return lo;
}

__global__ __launch_bounds__(256) void pool_kernel(const __half* __restrict__ x,
    const int* __restrict__ batch, const float* __restrict__ bs,
    const float* __restrict__ bq, const float* __restrict__ g,
    const float* __restrict__ b, float* __restrict__ pp, float* __restrict__ gcnt) {
  int gr = blockIdx.x, chunk = blockIdx.y;
  int f = threadIdx.x & 127, sub = threadIdx.x >> 7;
  float s0 = 0.f, q0 = 0.f;
#pragma unroll
  for (int i = 0; i < NBUCKET; ++i) {
    s0 += bs[i * 128 + f];
    q0 += bq[i * 128 + f];
  }
  float mu = s0 * (1.0f / N_NODES);
  float var = fmaxf(q0 * (1.0f / N_NODES) - mu * mu, 0.f);
  float sc = g[f] * rsqrtf(var + BN_EPS);
  float sh = fmaf(-mu, sc, b[f]);

  int lo = lower_bound_batch(batch, gr);
  int hi = lower_bound_batch(batch, gr + 1);
  int cnt = hi - lo;
  int per = (cnt + 7) >> 3;
  int s = lo + chunk * per;
  int e = min(s + per, hi);
  float acc = 0.f;
  for (int n = s + sub; n < e; n += 2)
    acc += fmaxf(fmaf(__half2float(x[(size_t)n * 128 + f]), sc, sh), 0.f);
  __shared__ float red[2][128];
  red[sub][f] = acc;
  __syncthreads();
  if (sub == 0) pp[((size_t)gr * 8 + chunk) * 128 + f] = red[0][f] + red[1][f];
  if (threadIdx.x == 0 && chunk == 0) gcnt[gr] = (float)cnt;
}

// ---------------- final MLP: relu(pooled/cnt @ W1 + b1) @ W2 + b2 ----------------
__global__ __launch_bounds__(256) void mlp_kernel(const float* __restrict__ pp,
    const float* __restrict__ gcnt, const float* __restrict__ w1, const float* __restrict__ b1,
    const float* __restrict__ w2, const float* __restrict__ b2, float* __restrict__ out) {
  int g = blockIdx.x, t = threadIdx.x;
  __shared__ float p[128];
  __shared__ float hbuf[256];
  if (t < 128) {
    float s = 0.f;
#pragma unroll
    for (int c = 0; c < 8; ++c) s += pp[((size_t)g * 8 + c) * 128 + t];
    p[t] = s / fmaxf(gcnt[g], 1.0f);
  }
  __syncthreads();
  float acc = b1[t];
  for (int k = 0; k < 128; ++k) acc = fmaf(p[k], w1[k * 256 + t], acc);
  hbuf[t] = fmaxf(acc, 0.f);
  __syncthreads();
  if (t < 10) {
    float o = b2[t];
    for (int k = 0; k < 256; ++k) o = fmaf(hbuf[k], w2[k * 10 + t], o);
    out[g * 10 + t] = o;
  }
}

// ---------------- launch ----------------
extern "C" void kernel_launch(void* const* d_in, const int* in_sizes, int n_in,
                              void* d_out, int out_size, void* d_ws, size_t ws_size,
                              hipStream_t stream) {
  const int* x_node = (const int*)d_in[0];
  const int* eidx = (const int*)d_in[1];
  const int* batch = (const int*)d_in[2];
  const float* emb = (const float*)d_in[3];
  const float* cw1 = (const float*)d_in[4];
  const float* cb1 = (const float*)d_in[5];
  const float* bn1g = (const float*)d_in[6];
  const float* bn1b = (const float*)d_in[7];
  const float* cw2 = (const float*)d_in[8];
  const float* cb2 = (const float*)d_in[9];
  const float* bn2g = (const float*)d_in[10];
  const float* bn2b = (const float*)d_in[11];
  const float* l1w = (const float*)d_in[12];
  const float* l1b = (const float*)d_in[13];
  const float* l2w = (const float*)d_in[14];
  const float* l2b = (const float*)d_in[15];
  float* out = (float*)d_out;

  char* ws = (char*)d_ws;
  size_t off = 0;
  auto carve = [&](size_t bytes) -> void* {
    void* p = ws + off;
    off += (bytes + 255) & ~(size_t)255;
    return p;
  };
  __half* xh   = (__half*)carve((size_t)N_NODES * D * 2);  // embed output
  __half* abuf = (__half*)carve((size_t)N_NODES * D * 2);  // agg output
  __half* ybuf = (__half*)carve((size_t)N_NODES * D * 2);  // gemm1 raw z1
  __half* zbuf = (__half*)carve((size_t)N_NODES * D * 2);  // gemm2 raw z2
  int* counts = (int*)carve((size_t)N_NODES * 4);
  int* offsets = (int*)carve((size_t)(N_NODES + 1) * 4);
  int* cursor = (int*)carve((size_t)N_NODES * 4);
  int* col = (int*)carve((size_t)N_EDGES * 4);
  int* partials = (int*)carve(64 * 4);
  float* buckets = (float*)carve((size_t)16 * NBUCKET * 128 * 4);
  float* scaleb = (float*)carve(4 * 128 * 4);   // bn2 scale, layers 0-2 used
  float* shiftb = (float*)carve(4 * 128 * 4);
  float* pp = (float*)carve(64 * 8 * 128 * 4);
  float* gcnt = (float*)carve(64 * 4);
  unsigned short* Whb = (unsigned short*)carve((size_t)8 * D * D * 2);
  (void)ws_size;
  (void)in_sizes;
  (void)n_in;
  (void)out_size;

  const int* srcp = eidx;
  const int* dstp = eidx + N_EDGES;

  setup_kernel<<<EMB_NB + ZERO_NB + RPK_NB, 256, 0, stream>>>(
      x_node, emb, xh, counts, buckets, cw1, cw2, Whb);
  count_kernel<<<EB, 256, 0, stream>>>(dstp, counts);
  scan_block_kernel<<<SCAN_NB, 256, 0, stream>>>(counts, offsets, partials);
  add_offsets_kernel<<<(N_NODES + 255) / 256, 256, 0, stream>>>(offsets, partials, cursor);
  fill_csr_kernel<<<EB, 256, 0, stream>>>(srcp, dstp, cursor, col);

  const size_t BSZ = (size_t)NBUCKET * 128;
  for (int l = 0; l < N_LAYERS; ++l) {
    float* b1s = buckets + (l * 4 + 0) * BSZ;
    float* b1q = buckets + (l * 4 + 1) * BSZ;
    float* b2s = buckets + (l * 4 + 2) * BSZ;
    float* b2q = buckets + (l * 4 + 3) * BSZ;
    float* sc2 = scaleb + l * 128;
    float* sh2 = shiftb + l * 128;
    const float* scp = scaleb + (l - 1) * 128;  // prev layer bn2
    const float* shp = shiftb + (l - 1) * 128;
    const unsigned short* W1h = Whb + (size_t)(l * 2) * D * D;
    const unsigned short* W2h = Whb + (size_t)(l * 2 + 1) * D * D;

    if (l == 0)
      agg_kernel<false><<<12500, 256, 0, stream>>>(xh, offsets, col, nullptr, nullptr, abuf);
    else
      agg_kernel<true><<<12500, 256, 0, stream>>>(zbuf, offsets, col, scp, shp, abuf);
    gemm_f16_kernel<false><<<GB, 256, 0, stream>>>(abuf, W1h, cb1 + l * D,
        nullptr, nullptr, nullptr, nullptr, ybuf, b1s, b1q);
    gemm_f16_kernel<true><<<GB, 256, 0, stream>>>(ybuf, W2h, cb2 + l * D,
        b1s, b1q, bn1g + l * D, bn1b + l * D, zbuf, b2s, b2q);
    if (l < N_LAYERS - 1)
      finalize_kernel<<<1, 128, 0, stream>>>(b2s, b2q, bn2g + l * D, bn2b + l * D,
                                             sc2, sh2);
  }

  pool_kernel<<<dim3(64, 8), 256, 0, stream>>>(zbuf, batch,
      buckets + (3 * 4 + 2) * BSZ, buckets + (3 * 4 + 3) * BSZ,
      bn2g + 3 * D, bn2b + 3 * D, pp, gcnt);
  mlp_kernel<<<64, 256, 0, stream>>>(pp, gcnt, l1w, l1b, l2w, l2b, out);
}

// Round 17
// 297.032 us; speedup vs baseline: 1.1366x; 1.0045x over previous
//
#include <hip/hip_runtime.h>
#include <hip/hip_fp16.h>

#define N_NODES 50000
#define N_EDGES 600000
#define N_GRAPHS 64
#define N_LAYERS 4
#define D 128
#define BN_EPS 1e-5f

#define SCAN_NB 49   // ceil(50000/1024)
#define GB 782       // gemm grid (ceil(50000/64))
#define NBUCKET 8
#define EB 586       // edge-batch grid: 600000 / (256*4)

// setup mega-kernel block ranges
#define EMB_NB 6250
#define ZERO_NB 14
#define RPK_NB 8

typedef __attribute__((ext_vector_type(8))) short short8;
typedef __attribute__((ext_vector_type(8))) _Float16 half8;
typedef __attribute__((ext_vector_type(4))) float f32x4;

__device__ __forceinline__ float half_bits_to_f32(short b) {
  union { unsigned short u; __half h; } cv;
  cv.u = (unsigned short)b;
  return __half2float(cv.h);
}
__device__ __forceinline__ unsigned short f32_to_half_bits(float f) {
  union { __half h; unsigned short u; } cv;
  cv.h = __float2half(f);
  return cv.u;
}

// ---- setup mega-kernel: embed | zero(counts + stat buckets) | W repack ----
__global__ __launch_bounds__(256) void setup_kernel(const int* __restrict__ idx,
    const float* __restrict__ emb, __half* __restrict__ xh,
    int* __restrict__ counts, float* __restrict__ buckets,
    const float* __restrict__ cw1, const float* __restrict__ cw2,
    unsigned short* __restrict__ Wh) {
  int bb = blockIdx.x;
  int t = threadIdx.x;
  if (bb < EMB_NB) {
    int tid = bb * 256 + t;
    if (tid >= N_NODES * 32) return;
    int n = tid >> 5, c4 = tid & 31;
    int e = idx[n];
    float4 v = ((const float4*)emb)[(size_t)e * 32 + c4];
    __half2 a = __float22half2_rn(make_float2(v.x, v.y));
    __half2 b = __float22half2_rn(make_float2(v.z, v.w));
    ((__half2*)xh)[(size_t)tid * 2] = a;
    ((__half2*)xh)[(size_t)tid * 2 + 1] = b;
  } else if (bb < EMB_NB + ZERO_NB) {
    int tid = (bb - EMB_NB) * 256 + t;
    for (int i = tid; i < N_NODES; i += ZERO_NB * 256) counts[i] = 0;
    for (int i = tid; i < 16 * NBUCKET * 128; i += ZERO_NB * 256) buckets[i] = 0.f;
  } else {
    int b = bb - (EMB_NB + ZERO_NB);  // 0..7 = l*2 + which
    int l = b >> 1, which = b & 1;
    const float* Wm = (which ? cw2 : cw1) + (size_t)l * D * D;
    unsigned short* outh = Wh + (size_t)b * D * D;
    for (int T = t; T < 2048; T += 256) {
      int ks = T >> 9, ct = (T >> 6) & 7, lane = T & 63;
      int kbase = ks * 32 + ((lane >> 4) << 3);
      int c = ct * 16 + (lane & 15);
      unsigned short hs[8];
#pragma unroll
      for (int e = 0; e < 8; ++e) {
        float v = Wm[(size_t)(kbase + e) * D + c];
        hs[e] = f32_to_half_bits(v);
      }
      *(ushort4*)(outh + (size_t)T * 8)     = *(ushort4*)&hs[0];
      *(ushort4*)(outh + (size_t)T * 8 + 4) = *(ushort4*)&hs[4];
    }
  }
}

// ---------------- CSR build (4 edges/thread) ----------------
__global__ __launch_bounds__(256) void count_kernel(const int* __restrict__ dst,
    int* __restrict__ counts) {
  int i = blockIdx.x * 256 + threadIdx.x;  // quad index
  if (i * 4 >= N_EDGES) return;
  int4 d = ((const int4*)dst)[i];
  atomicAdd(&counts[d.x], 1);
  atomicAdd(&counts[d.y], 1);
  atomicAdd(&counts[d.z], 1);
  atomicAdd(&counts[d.w], 1);
}

// scan within 1024-chunks; offsets/cursor hold CHUNK-LOCAL exclusive offsets.
// partials[b] = chunk total; last chunk also writes offsets[N_NODES] (local total).
__global__ __launch_bounds__(256) void scan_block_kernel(const int* __restrict__ counts,
    int* __restrict__ offsets, int* __restrict__ cursor, int* __restrict__ partials) {
  __shared__ int s[256];
  int t = threadIdx.x;
  int base = blockIdx.x * 1024 + t * 4;
  int v[4];
#pragma unroll
  for (int i = 0; i < 4; ++i) v[i] = (base + i < N_NODES) ? counts[base + i] : 0;
  int tsum = v[0] + v[1] + v[2] + v[3];
  s[t] = tsum;
  __syncthreads();
  for (int off = 1; off < 256; off <<= 1) {
    int add = (t >= off) ? s[t - off] : 0;
    __syncthreads();
    s[t] += add;
    __syncthreads();
  }
  int run = s[t] - tsum;  // exclusive within block
#pragma unroll
  for (int i = 0; i < 4; ++i) {
    if (base + i < N_NODES) {
      offsets[base + i] = run;
      cursor[base + i] = run;
    }
    run += v[i];
  }
  if (t == 255) {
    partials[blockIdx.x] = s[255];
    if (blockIdx.x == SCAN_NB - 1) offsets[N_NODES] = s[255];
  }
}

// fill: local cursor + global chunk prefix. Prefix computed by wave 0 at kernel
// entry (all lanes live) and staged through LDS — safe under later divergence.
// Block 0 persists the prefix to gpre for agg.
__global__ __launch_bounds__(256) void fill_csr_kernel(const int* __restrict__ src,
    const int* __restrict__ dst, const int* __restrict__ partials,
    int* __restrict__ cursor, int* __restrict__ col, int* __restrict__ gpre) {
  __shared__ int preS[SCAN_NB];
  if (threadIdx.x < 64) {
    int lane = threadIdx.x;
    int pv = (lane < SCAN_NB) ? partials[lane] : 0;
    int inc = pv;
#pragma unroll
    for (int o = 1; o < 64; o <<= 1) {
      int u = __shfl_up(inc, o, 64);
      if (lane >= o) inc += u;
    }
    int exc = inc - pv;  // exclusive prefix of partials
    if (lane < SCAN_NB) {
      preS[lane] = exc;
      if (blockIdx.x == 0) gpre[lane] = exc;
    }
  }
  __syncthreads();

  int i = blockIdx.x * 256 + threadIdx.x;  // quad index
  if (i * 4 >= N_EDGES) return;
  int4 d = ((const int4*)dst)[i];
  int4 s = ((const int4*)src)[i];
  int p0 = atomicAdd(&cursor[d.x], 1) + preS[d.x >> 10];
  int p1 = atomicAdd(&cursor[d.y], 1) + preS[d.y >> 10];
  int p2 = atomicAdd(&cursor[d.z], 1) + preS[d.z >> 10];
  int p3 = atomicAdd(&cursor[d.w], 1) + preS[d.w >> 10];
  col[p0] = s.x;
  col[p1] = s.y;
  col[p2] = s.z;
  col[p3] = s.w;
}

// ---- aggregation: h = t(x[node]) + sum t(x[src]); t = optional prev-layer bn-relu ----
template <bool TRANS>
__global__ __launch_bounds__(256) void agg_kernel(const __half* __restrict__ xh,
    const int* __restrict__ offsets, const int* __restrict__ gpre,
    const int* __restrict__ col,
    const float* __restrict__ scale, const float* __restrict__ shift,
    __half* __restrict__ h) {
  int node = blockIdx.x * 4 + (threadIdx.x >> 6);
  int lane = threadIdx.x & 63;
  float2 scl, shl;
  if (TRANS) {
    scl = ((const float2*)scale)[lane];
    shl = ((const float2*)shift)[lane];
  }
  const __half2* x2 = (const __half2*)xh;
  float2 self = __half22float2(x2[(size_t)node * 64 + lane]);
  float2 acc;
  if (TRANS) {
    acc.x = fmaxf(fmaf(self.x, scl.x, shl.x), 0.f);
    acc.y = fmaxf(fmaf(self.y, scl.y, shl.y), 0.f);
  } else {
    acc = self;
  }
  int beg = offsets[node] + gpre[node >> 10];
  int end = offsets[node + 1] + gpre[(node + 1) >> 10];
  for (int e = beg; e < end; e += 8) {
    int idx[8];
    bool val[8];
#pragma unroll
    for (int j = 0; j < 8; ++j) {
      val[j] = (e + j) < end;
      idx[j] = val[j] ? (e + j) : e;
    }
    int sidx[8];
#pragma unroll
    for (int j = 0; j < 8; ++j) sidx[j] = col[idx[j]];
    float2 ff[8];
#pragma unroll
    for (int j = 0; j < 8; ++j) ff[j] = __half22float2(x2[(size_t)sidx[j] * 64 + lane]);
#pragma unroll
    for (int j = 0; j < 8; ++j) {
      float2 v = ff[j];
      if (TRANS) {
        v.x = fmaxf(fmaf(v.x, scl.x, shl.x), 0.f);
        v.y = fmaxf(fmaf(v.y, scl.y, shl.y), 0.f);
      }
      if (val[j]) {
        acc.x += v.x;
        acc.y += v.y;
      }
    }
  }
  ((__half2*)h)[(size_t)node * 64 + lane] = __float22half2_rn(acc);
}

// ---- fp16 MFMA GEMM (single-plane fp16 W), 64-row tile, 256 thr ----
template <bool FIN_IN>
__global__ __launch_bounds__(256) void gemm_f16_kernel(
    const __half* __restrict__ A, const unsigned short* __restrict__ Wh,
    const float* __restrict__ bias,
    const float* __restrict__ ibs, const float* __restrict__ ibq,
    const float* __restrict__ bng, const float* __restrict__ bnb,
    __half* __restrict__ Y, float* __restrict__ obs, float* __restrict__ obq) {
  __shared__ unsigned short AL[64][136];  // fp16 bits; +8 pad
  __shared__ float scL[128], shL[128];
  int t = threadIdx.x;
  int row0 = blockIdx.x * 64;
  int lane = t & 63;
  int wv = t >> 6;

  if (FIN_IN) {
    if (t < 128) {
      float s = 0.f, q = 0.f;
#pragma unroll
      for (int i = 0; i < NBUCKET; ++i) {
        s += ibs[i * 128 + t];
        q += ibq[i * 128 + t];
      }
      float mu = s * (1.0f / N_NODES);
      float var = fmaxf(q * (1.0f / N_NODES) - mu * mu, 0.f);
      float sc = bng[t] * rsqrtf(var + BN_EPS);
      scL[t] = sc;
      shL[t] = fmaf(-mu, sc, bnb[t]);
    }
    __syncthreads();
  }

#pragma unroll
  for (int i = 0; i < 4; ++i) {
    int s = i * 256 + t;
    int r = s >> 4, c8 = s & 15;
    int row = row0 + r;
    short8 v = {0, 0, 0, 0, 0, 0, 0, 0};
    if (row < N_NODES) v = *(const short8*)(A + (size_t)row * D + c8 * 8);
    if (FIN_IN) {
      float4 sc0 = *(const float4*)&scL[c8 * 8];
      float4 sc1 = *(const float4*)&scL[c8 * 8 + 4];
      float4 sh0 = *(const float4*)&shL[c8 * 8];
      float4 sh1 = *(const float4*)&shL[c8 * 8 + 4];
      float scv[8] = {sc0.x, sc0.y, sc0.z, sc0.w, sc1.x, sc1.y, sc1.z, sc1.w};
      float shv[8] = {sh0.x, sh0.y, sh0.z, sh0.w, sh1.x, sh1.y, sh1.z, sh1.w};
      short8 o;
#pragma unroll
      for (int j = 0; j < 8; ++j) {
        float f = fmaxf(fmaf(half_bits_to_f32(v[j]), scv[j], shv[j]), 0.f);
        o[j] = (short)f32_to_half_bits(f);
      }
      v = o;
    }
    *(short8*)&AL[r][c8 * 8] = v;
  }
  __syncthreads();

  f32x4 acc[4][2];
#pragma unroll
  for (int rt = 0; rt < 4; ++rt)
#pragma unroll
    for (int c = 0; c < 2; ++c) acc[rt][c] = (f32x4){0.f, 0.f, 0.f, 0.f};

  int arow_lo = lane & 15;
  int kgrp = (lane >> 4) * 8;
#pragma unroll
  for (int ks = 0; ks < 4; ++ks) {
    size_t wbase = ((size_t)(ks * 8 + wv * 2) * 64 + lane) * 8;
    half8 wh0 = __builtin_bit_cast(half8, *(const short8*)(Wh + wbase));
    half8 wh1 = __builtin_bit_cast(half8, *(const short8*)(Wh + wbase + 512));
#pragma unroll
    for (int rt = 0; rt < 4; ++rt) {
      half8 av = __builtin_bit_cast(half8,
          *(const short8*)&AL[rt * 16 + arow_lo][ks * 32 + kgrp]);
      acc[rt][0] = __builtin_amdgcn_mfma_f32_16x16x32_f16(av, wh0, acc[rt][0], 0, 0, 0);
      acc[rt][1] = __builtin_amdgcn_mfma_f32_16x16x32_f16(av, wh1, acc[rt][1], 0, 0, 0);
    }
  }

  __syncthreads();  // reuse AL as fp16 output staging

  int rsub = (lane >> 4) << 2;
  int cl = lane & 15;
  int bkt = (blockIdx.x & (NBUCKET - 1)) * 128;
#pragma unroll
  for (int cti = 0; cti < 2; ++cti) {
    int c = wv * 32 + cti * 16 + cl;
    float b = bias[c];
    float s = 0.f, q = 0.f;
#pragma unroll
    for (int rt = 0; rt < 4; ++rt) {
#pragma unroll
      for (int r = 0; r < 4; ++r) {
        int rl = rt * 16 + rsub + r;
        float y = acc[rt][cti][r] + b;
        ((__half*)&AL[rl][0])[c] = __float2half(y);
        if (row0 + rl < N_NODES) {
          s += y;
          q += y * y;
        }
      }
    }
    s += __shfl_xor(s, 16, 64);
    s += __shfl_xor(s, 32, 64);
    q += __shfl_xor(q, 16, 64);
    q += __shfl_xor(q, 32, 64);
    if (lane < 16) {
      atomicAdd(&obs[bkt + c], s);
      atomicAdd(&obq[bkt + c], q);
    }
  }
  __syncthreads();
#pragma unroll
  for (int i = 0; i < 4; ++i) {
    int s = i * 256 + t;
    int r = s >> 4, c8 = s & 15;
    int row = row0 + r;
    if (row < N_NODES) {
      ushort4 a = *(ushort4*)&AL[r][c8 * 8];
      ushort4 b = *(ushort4*)&AL[r][c8 * 8 + 4];
      *(ushort4*)((unsigned short*)Y + (size_t)row * D + c8 * 8)     = a;
      *(ushort4*)((unsigned short*)Y + (size_t)row * D + c8 * 8 + 4) = b;
    }
  }
}

// ---- BN finalize (layers 0-2): 1 block, reduce NBUCKET x 128 -> scale/shift ----
__global__ __launch_bounds__(128) void finalize_kernel(const float* __restrict__ bs,
    const float* __restrict__ bq, const float* __restrict__ g, const float* __restrict__ b,
    float* __restrict__ scale, float* __restrict__ shift) {
  int c = threadIdx.x;
  float s = 0.f, q = 0.f;
#pragma unroll
  for (int i = 0; i < NBUCKET; ++i) {
    s += bs[i * 128 + c];
    q += bq[i * 128 + c];
  }
  float mu = s * (1.0f / N_NODES);
  float var = fmaxf(q * (1.0f / N_NODES) - mu * mu, 0.f);
  float sc = g[c] * rsqrtf(var + BN_EPS);
  scale[c] = sc;
  shift[c] = fmaf(-mu, sc, b[c]);
}

// ---- pooling with inlined layer-3 bn finalize ----
__device__ __forceinline__ int lower_bound_batch(const int* __restrict__ batch, int key) {
  int lo = 0, hi = N_NODES;
  while (lo < hi) {
    int mid = (lo + hi) >> 1;
    if (batch[mid] < key) lo = mid + 1; else hi = mid;
  }
  return lo;
}

__global__ __launch_bounds__(256) void pool_kernel(const __half* __restrict__ x,
    const int* __restrict__ batch, const float* __restrict__ bs,
    const float* __restrict__ bq, const float* __restrict__ g,
    const float* __restrict__ b, float* __restrict__ pp, float* __restrict__ gcnt) {
  int gr = blockIdx.x, chunk = blockIdx.y;
  int f = threadIdx.x & 127, sub = threadIdx.x >> 7;
  float s0 = 0.f, q0 = 0.f;
#pragma unroll
  for (int i = 0; i < NBUCKET; ++i) {
    s0 += bs[i * 128 + f];
    q0 += bq[i * 128 + f];
  }
  float mu = s0 * (1.0f / N_NODES);
  float var = fmaxf(q0 * (1.0f / N_NODES) - mu * mu, 0.f);
  float sc = g[f] * rsqrtf(var + BN_EPS);
  float sh = fmaf(-mu, sc, b[f]);

  int lo = lower_bound_batch(batch, gr);
  int hi = lower_bound_batch(batch, gr + 1);
  int cnt = hi - lo;
  int per = (cnt + 7) >> 3;
  int s = lo + chunk * per;
  int e = min(s + per, hi);
  float acc = 0.f;
  for (int n = s + sub; n < e; n += 2)
    acc += fmaxf(fmaf(__half2float(x[(size_t)n * 128 + f]), sc, sh), 0.f);
  __shared__ float red[2][128];
  red[sub][f] = acc;
  __syncthreads();
  if (sub == 0) pp[((size_t)gr * 8 + chunk) * 128 + f] = red[0][f] + red[1][f];
  if (threadIdx.x == 0 && chunk == 0) gcnt[gr] = (float)cnt;
}

// ---------------- final MLP: relu(pooled/cnt @ W1 + b1) @ W2 + b2 ----------------
__global__ __launch_bounds__(256) void mlp_kernel(const float* __restrict__ pp,
    const float* __restrict__ gcnt, const float* __restrict__ w1, const float* __restrict__ b1,
    const float* __restrict__ w2, const float* __restrict__ b2, float* __restrict__ out) {
  int g = blockIdx.x, t = threadIdx.x;
  __shared__ float p[128];
  __shared__ float hbuf[256];
  if (t < 128) {
    float s = 0.f;
#pragma unroll
    for (int c = 0; c < 8; ++c) s += pp[((size_t)g * 8 + c) * 128 + t];
    p[t] = s / fmaxf(gcnt[g], 1.0f);
  }
  __syncthreads();
  float acc = b1[t];
  for (int k = 0; k < 128; ++k) acc = fmaf(p[k], w1[k * 256 + t], acc);
  hbuf[t] = fmaxf(acc, 0.f);
  __syncthreads();
  if (t < 10) {
    float o = b2[t];
    for (int k = 0; k < 256; ++k) o = fmaf(hbuf[k], w2[k * 10 + t], o);
    out[g * 10 + t] = o;
  }
}

// ---------------- launch ----------------
extern "C" void kernel_launch(void* const* d_in, const int* in_sizes, int n_in,
                              void* d_out, int out_size, void* d_ws, size_t ws_size,
                              hipStream_t stream) {
  const int* x_node = (const int*)d_in[0];
  const int* eidx = (const int*)d_in[1];
  const int* batch = (const int*)d_in[2];
  const float* emb = (const float*)d_in[3];
  const float* cw1 = (const float*)d_in[4];
  const float* cb1 = (const float*)d_in[5];
  const float* bn1g = (const float*)d_in[6];
  const float* bn1b = (const float*)d_in[7];
  const float* cw2 = (const float*)d_in[8];
  const float* cb2 = (const float*)d_in[9];
  const float* bn2g = (const float*)d_in[10];
  const float* bn2b = (const float*)d_in[11];
  const float* l1w = (const float*)d_in[12];
  const float* l1b = (const float*)d_in[13];
  const float* l2w = (const float*)d_in[14];
  const float* l2b = (const float*)d_in[15];
  float* out = (float*)d_out;

  char* ws = (char*)d_ws;
  size_t off = 0;
  auto carve = [&](size_t bytes) -> void* {
    void* p = ws + off;
    off += (bytes + 255) & ~(size_t)255;
    return p;
  };
  __half* xh   = (__half*)carve((size_t)N_NODES * D * 2);  // embed output
  __half* abuf = (__half*)carve((size_t)N_NODES * D * 2);  // agg output
  __half* ybuf = (__half*)carve((size_t)N_NODES * D * 2);  // gemm1 raw z1
  __half* zbuf = (__half*)carve((size_t)N_NODES * D * 2);  // gemm2 raw z2
  int* counts = (int*)carve((size_t)N_NODES * 4);
  int* offsets = (int*)carve((size_t)(N_NODES + 1) * 4);
  int* cursor = (int*)carve((size_t)N_NODES * 4);
  int* col = (int*)carve((size_t)N_EDGES * 4);
  int* partials = (int*)carve(64 * 4);
  int* gpre = (int*)carve(64 * 4);
  float* buckets = (float*)carve((size_t)16 * NBUCKET * 128 * 4);
  float* scaleb = (float*)carve(4 * 128 * 4);   // bn2 scale, layers 0-2 used
  float* shiftb = (float*)carve(4 * 128 * 4);
  float* pp = (float*)carve(64 * 8 * 128 * 4);
  float* gcnt = (float*)carve(64 * 4);
  unsigned short* Whb = (unsigned short*)carve((size_t)8 * D * D * 2);
  (void)ws_size;
  (void)in_sizes;
  (void)n_in;
  (void)out_size;

  const int* srcp = eidx;
  const int* dstp = eidx + N_EDGES;

  setup_kernel<<<EMB_NB + ZERO_NB + RPK_NB, 256, 0, stream>>>(
      x_node, emb, xh, counts, buckets, cw1, cw2, Whb);
  count_kernel<<<EB, 256, 0, stream>>>(dstp, counts);
  scan_block_kernel<<<SCAN_NB, 256, 0, stream>>>(counts, offsets, cursor, partials);
  fill_csr_kernel<<<EB, 256, 0, stream>>>(srcp, dstp, partials, cursor, col, gpre);

  const size_t BSZ = (size_t)NBUCKET * 128;
  for (int l = 0; l < N_LAYERS; ++l) {
    float* b1s = buckets + (l * 4 + 0) * BSZ;
    float* b1q = buckets + (l * 4 + 1) * BSZ;
    float* b2s = buckets + (l * 4 + 2) * BSZ;
    float* b2q = buckets + (l * 4 + 3) * BSZ;
    float* sc2 = scaleb + l * 128;
    float* sh2 = shiftb + l * 128;
    const float* scp = scaleb + (l - 1) * 128;  // prev layer bn2
    const float* shp = shiftb + (l - 1) * 128;
    const unsigned short* W1h = Whb + (size_t)(l * 2) * D * D;
    const unsigned short* W2h = Whb + (size_t)(l * 2 + 1) * D * D;

    if (l == 0)
      agg_kernel<false><<<12500, 256, 0, stream>>>(xh, offsets, gpre, col,
                                                   nullptr, nullptr, abuf);
    else
      agg_kernel<true><<<12500, 256, 0, stream>>>(zbuf, offsets, gpre, col,
                                                  scp, shp, abuf);
    gemm_f16_kernel<false><<<GB, 256, 0, stream>>>(abuf, W1h, cb1 + l * D,
        nullptr, nullptr, nullptr, nullptr, ybuf, b1s, b1q);
    gemm_f16_kernel<true><<<GB, 256, 0, stream>>>(ybuf, W2h, cb2 + l * D,
        b1s, b1q, bn1g + l * D, bn1b + l * D, zbuf, b2s, b2q);
    if (l < N_LAYERS - 1)
      finalize_kernel<<<1, 128, 0, stream>>>(b2s, b2q, bn2g + l * D, bn2b + l * D,
                                             sc2, sh2);
  }

  pool_kernel<<<dim3(64, 8), 256, 0, stream>>>(zbuf, batch,
      buckets + (3 * 4 + 2) * BSZ, buckets + (3 * 4 + 3) * BSZ,
      bn2g + 3 * D, bn2b + 3 * D, pp, gcnt);
  mlp_kernel<<<64, 256, 0, stream>>>(pp, gcnt, l1w, l1b, l2w, l2b, out);
}